// Round 14
// baseline (275.965 us; speedup 1.0000x reference)
//
#include <hip/hip_runtime.h>
#include <hip/hip_bf16.h>

#define NDIM 256   // IN_DIM
#define HDIM 128   // HID
#define NPAD 100352
#define LDS1_STRIDE 264      // bf16 row stride for GEMM1 staging (256 + 8 pad)
#define LDS2_STRIDE 136      // bf16 row stride for aggdec staging (128 + 8 pad)
#define P2CAP 6144           // edges cached in LDS per bucket (expected ~4092)

typedef __bf16 bf16_t;
typedef bf16_t bf16x2 __attribute__((ext_vector_type(2)));
typedef bf16_t bf16x4 __attribute__((ext_vector_type(4)));
typedef bf16_t bf16x8 __attribute__((ext_vector_type(8)));
typedef float f32x2 __attribute__((ext_vector_type(2)));
typedef float f32x4 __attribute__((ext_vector_type(4)));

__device__ __forceinline__ float bflo(unsigned u) { return __uint_as_float(u << 16); }
__device__ __forceinline__ float bfhi(unsigned u) { return __uint_as_float(u & 0xffff0000u); }

// ---------------- prep: pack both weights into MFMA fragment order ----------------
__global__ __launch_bounds__(256) void k_prep(const float* __restrict__ We, bf16_t* __restrict__ wpe,
                                              const float* __restrict__ Wd, bf16_t* __restrict__ wpd) {
    const int b = blockIdx.x, t = threadIdx.x;
    const bool enc = b < 16;
    const int i = (enc ? b : b - 16) * 256 + t;  // 0..4095
    const int lane = i & 63;
    const int fr = lane & 15, kg = lane >> 4;
    int nf, kk32, K, NF;
    const float* W;
    bf16_t* wp;
    if (enc) { nf = (i >> 6) & 7;  kk32 = i >> 9;  K = NDIM; NF = 8;  W = We; wp = wpe; }
    else     { nf = (i >> 6) & 15; kk32 = i >> 10; K = HDIM; NF = 16; W = Wd; wp = wpd; }
    const float* src = &W[(size_t)(nf * 16 + fr) * K + kk32 * 32 + kg * 8];
    const f32x4 a0 = *reinterpret_cast<const f32x4*>(src);
    const f32x4 a1 = *reinterpret_cast<const f32x4*>(src + 4);
    bf16x8 o;
    o[0] = (bf16_t)a0[0]; o[1] = (bf16_t)a0[1]; o[2] = (bf16_t)a0[2]; o[3] = (bf16_t)a0[3];
    o[4] = (bf16_t)a1[0]; o[5] = (bf16_t)a1[1]; o[6] = (bf16_t)a1[2]; o[7] = (bf16_t)a1[3];
    reinterpret_cast<bf16x8*>(wp)[(kk32 * NF + nf) * 64 + lane] = o;
}

// ---------------- MFMA ladder + epilogue (af already in regs) ----------------
// mfma_f32_16x16x32_bf16: A lane l -> row l&15, k=(l>>4)*8+j; B lane l -> col l&15,
// same k; C/D lane l reg i -> col l&15, row (l>>4)*4+i. [m89]
// f32-output path (xrec) uses non-temporal stores: output is never re-read.
template<int K, int NC, bool OUT_BF16>
__device__ __forceinline__ void mfma_epi(const bf16x8* af,
                                         const bf16_t* __restrict__ Wp,
                                         const float* __restrict__ bias,
                                         void* __restrict__ Cout,
                                         const int bid, const int nrows) {
    const int lane = threadIdx.x & 63;
    const int wv = threadIdx.x >> 6;
    const int fr = lane & 15;
    const int kg = lane >> 4;
    constexpr int NF = NC / 16, NK = K / 32;

    const bf16x8* wp = reinterpret_cast<const bf16x8*>(Wp);
    f32x4 acc[NF];
    const f32x4 zero4 = {0.f, 0.f, 0.f, 0.f};
    #pragma unroll
    for (int nf = 0; nf < NF; ++nf) acc[nf] = zero4;

    #pragma unroll
    for (int k = 0; k < NK; ++k) {
        #pragma unroll
        for (int nf = 0; nf < NF; ++nf)
            acc[nf] = __builtin_amdgcn_mfma_f32_16x16x32_bf16(af[k], wp[(k * NF + nf) * 64 + lane], acc[nf], 0, 0, 0);
    }

    const long long rbase = (long long)bid * 64 + wv * 16 + kg * 4;
    #pragma unroll
    for (int nf = 0; nf < NF; ++nf) {
        const int c = nf * 16 + fr;
        const float bv = bias ? bias[c] : 0.f;
        #pragma unroll
        for (int i = 0; i < 4; ++i) {
            const long long r = rbase + i;
            if (r < nrows) {
                const float v = acc[nf][i] + bv;
                if (OUT_BF16) ((bf16_t*)Cout)[r * NC + c] = (bf16_t)v;
                else          __builtin_nontemporal_store(v, &((float*)Cout)[r * NC + c]);
            }
        }
    }
}

// ---------------- GEMM1 body: LDS-staged A (f32 -> bf16), 64 rows/block ----------------
// x loads are non-temporal (stream-once; keep L2/L3 for hb).
__device__ __forceinline__ void gemm1_body(const int bid, const float* __restrict__ x,
                                           const bf16_t* __restrict__ wpe,
                                           bf16_t* __restrict__ hb, const int nrows,
                                           bf16_t* lds) {
    const int t = threadIdx.x;
    const long long rowbase = (long long)bid * 64;
    #pragma unroll
    for (int p = 0; p < 16; ++p) {
        const int s = p * 256 + t;          // float4 slot
        const int r = s >> 6, c4 = s & 63;
        long long gr = rowbase + r;
        if (gr >= nrows) gr = nrows - 1;
        const f32x4 v = __builtin_nontemporal_load(reinterpret_cast<const f32x4*>(&x[gr * NDIM + c4 * 4]));
        bf16x4 o;
        o[0] = (bf16_t)v[0]; o[1] = (bf16_t)v[1]; o[2] = (bf16_t)v[2]; o[3] = (bf16_t)v[3];
        *reinterpret_cast<bf16x4*>(&lds[r * LDS1_STRIDE + c4 * 4]) = o;
    }
    __syncthreads();
    const int lane = t & 63, wv = t >> 6, fr = lane & 15, kg = lane >> 4;
    bf16x8 af[8];
    #pragma unroll
    for (int k = 0; k < 8; ++k)
        af[k] = *reinterpret_cast<const bf16x8*>(&lds[(wv * 16 + fr) * LDS1_STRIDE + k * 32 + kg * 8]);
    mfma_epi<NDIM, HDIM, true>(af, wpe, nullptr, hb, bid, nrows);
}

// ---------------- P1a body: per-block bucket histogram (LDS only) ----------------
__device__ __forceinline__ void p1a_body(const int blk, const int* __restrict__ col,
                                         int* __restrict__ bcnt, const int E_,
                                         const int nbkt, const int epb, int* lhist) {
    const int t = threadIdx.x;
    for (int i = t; i < nbkt; i += 256) lhist[i] = 0;
    __syncthreads();
    const int base = blk * epb;
    const int cnt = min(E_ - base, epb);
    for (int i = t; i < cnt; i += 256)
        atomicAdd(&lhist[col[base + i] >> 8], 1);
    __syncthreads();
    for (int i = t; i < nbkt; i += 256)
        bcnt[i * 256 + blk] = lhist[i];     // bin-major layout
}

// ---------------- fused: GEMM1 (blocks < G1) + P1a (rest) ----------------
__global__ __launch_bounds__(256) void k_fused(const float* __restrict__ x,
                                               const bf16_t* __restrict__ wpe,
                                               bf16_t* __restrict__ hb, const int nrows,
                                               const int* __restrict__ col,
                                               int* __restrict__ bcnt,
                                               const int E_, const int nbkt, const int epb,
                                               const int G1) {
    __shared__ __align__(16) bf16_t lds[64 * LDS1_STRIDE];
    const int b = blockIdx.x;
    if (b < G1) gemm1_body(b, x, wpe, hb, nrows, lds);
    else        p1a_body(b - G1, col, bcnt, E_, nbkt, epb, (int*)lds);
}

// ---------------- hierarchical exclusive scan over bcnt[M] (3 passes) ----------------
__global__ __launch_bounds__(256) void k_scanB1(const int* __restrict__ bcnt,
                                                int* __restrict__ bsum, const int M) {
    __shared__ int s[256];
    const int b = blockIdx.x, t = threadIdx.x;
    const int i0 = b * 1024 + t * 4;
    int4 v = make_int4(0, 0, 0, 0);
    if (i0 + 4 <= M) v = *reinterpret_cast<const int4*>(&bcnt[i0]);
    else if (i0 < M) {
        const int k = M - i0;
        v.x = bcnt[i0];
        if (k > 1) v.y = bcnt[i0 + 1];
        if (k > 2) v.z = bcnt[i0 + 2];
    }
    s[t] = v.x + v.y + v.z + v.w;
    __syncthreads();
    for (int d = 128; d > 0; d >>= 1) {
        if (t < d) s[t] += s[t + d];
        __syncthreads();
    }
    if (t == 0) bsum[b] = s[0];
}

__global__ __launch_bounds__(128) void k_scanB2(const int* __restrict__ bsum,
                                                int* __restrict__ bofs,
                                                int* __restrict__ bbase,
                                                const int nb, const int M) {
    __shared__ int s[128];
    const int t = threadIdx.x;
    const int v = (t < nb) ? bsum[t] : 0;
    s[t] = v;
    __syncthreads();
    for (int d = 1; d < 128; d <<= 1) {
        int xx = (t >= d) ? s[t - d] : 0;
        __syncthreads();
        s[t] += xx;
        __syncthreads();
    }
    if (t < nb) bofs[t] = s[t] - v;      // exclusive
    if (t == nb - 1) bbase[M] = s[t];    // total = E
}

__global__ __launch_bounds__(256) void k_scanB3(const int* __restrict__ bcnt,
                                                const int* __restrict__ bofs,
                                                int* __restrict__ bbase, const int M) {
    __shared__ int s[256];
    const int b = blockIdx.x, t = threadIdx.x;
    const int i0 = b * 1024 + t * 4;
    int4 v = make_int4(0, 0, 0, 0);
    if (i0 + 4 <= M) v = *reinterpret_cast<const int4*>(&bcnt[i0]);
    else if (i0 < M) {
        const int k = M - i0;
        v.x = bcnt[i0];
        if (k > 1) v.y = bcnt[i0 + 1];
        if (k > 2) v.z = bcnt[i0 + 2];
    }
    const int tsum = v.x + v.y + v.z + v.w;
    s[t] = tsum;
    __syncthreads();
    for (int d = 1; d < 256; d <<= 1) {
        int xx = (t >= d) ? s[t - d] : 0;
        __syncthreads();
        s[t] += xx;
        __syncthreads();
    }
    const int excl = s[t] - tsum + bofs[b];
    int4 o;
    o.x = excl; o.y = excl + v.x; o.z = o.y + v.y; o.w = o.z + v.z;
    if (i0 + 4 <= M) *reinterpret_cast<int4*>(&bbase[i0]) = o;
    else if (i0 < M) {
        const int k = M - i0;
        bbase[i0] = o.x;
        if (k > 1) bbase[i0 + 1] = o.y;
        if (k > 2) bbase[i0 + 2] = o.z;
    }
}

// ---------------- P1b: partition edges into buckets (private LDS cursors) ----------------
// pbuf entry: packed  r | ((c & 255) << 17)   (r < 2^17, only col low-8 needed by P2)
__global__ __launch_bounds__(256) void k_p1b(const int* __restrict__ row,
                                             const int* __restrict__ col,
                                             const int* __restrict__ bbase,
                                             int* __restrict__ pbuf,
                                             const int E_, const int nbkt, const int epb) {
    __shared__ int lcur[512];
    const int blk = blockIdx.x, t = threadIdx.x;
    for (int i = t; i < nbkt; i += 256) lcur[i] = bbase[i * 256 + blk];
    __syncthreads();
    const int base = blk * epb;
    const int cnt = min(E_ - base, epb);
    for (int i = t; i < cnt; i += 256) {
        const int c = col[base + i];
        const int r = row[base + i];
        const int pos = atomicAdd(&lcur[c >> 8], 1);
        pbuf[pos] = r | ((c & 255) << 17);
    }
}

// ---------------- P2: per-bucket CSR build + dinv + pre-scale hb rows by dinv ----------------
__global__ __launch_bounds__(256) void k_p2(const int* __restrict__ pbuf,
                                            const int* __restrict__ bbase,
                                            int* __restrict__ ebuf,
                                            int* __restrict__ goff, int* __restrict__ gcnt,
                                            float* __restrict__ dinv,
                                            unsigned* __restrict__ hbw,   // [N][64] bf16-pairs, scaled in place
                                            const int n, const int E_) {
    __shared__ int lcnt[256], lscan[256], lcur[256];
    __shared__ float ldinv[256];
    __shared__ __align__(16) int ecache[P2CAP];
    const int b = blockIdx.x, t = threadIdx.x;
    const int start = bbase[b * 256];
    const int end = bbase[(b + 1) * 256];
    const int size = end - start;
    const bool inlds = size <= P2CAP;
    lcnt[t] = 0; lcur[t] = 0;
    __syncthreads();
    if (inlds) {
        for (int i = t; i < size; i += 256) {
            const int e = pbuf[start + i];
            ecache[i] = e;
            atomicAdd(&lcnt[(e >> 17) & 255], 1);
        }
    } else {
        for (int i = t; i < size; i += 256)
            atomicAdd(&lcnt[(pbuf[start + i] >> 17) & 255], 1);
    }
    __syncthreads();
    const int v = lcnt[t];
    lscan[t] = v;
    __syncthreads();
    for (int d = 1; d < 256; d <<= 1) {
        int xx = (t >= d) ? lscan[t - d] : 0;
        __syncthreads();
        lscan[t] += xx;
        __syncthreads();
    }
    const int excl = lscan[t] - v;
    const int node = (b << 8) + t;
    float dvv = 0.f;
    if (node < n) {
        dvv = rsqrtf((float)(v + 1));
        goff[node] = start + excl;
        gcnt[node] = v;
        dinv[node] = dvv;
    }
    ldinv[t] = dvv;
    lscan[t] = excl;
    __syncthreads();
    for (int i = t; i < size; i += 256) {
        const int e = inlds ? ecache[i] : pbuf[start + i];
        const int li = (e >> 17) & 255;
        const int rk = atomicAdd(&lcur[li], 1);
        ebuf[start + lscan[li] + rk] = e & 0x1FFFF;
    }
    // pre-scale hb rows of this bucket: hb'[node] = hb[node] * dinv[node]
    const int wv = t >> 6, lane = t & 63;
    #pragma unroll 4
    for (int rr = wv * 64; rr < wv * 64 + 64; ++rr) {
        const int nd = (b << 8) + rr;
        if (nd >= n) break;
        const float dv = ldinv[rr];
        unsigned* p = &hbw[(size_t)nd * 64 + lane];
        const unsigned u = *p;
        bf16x2 pk;
        pk[0] = (bf16_t)(bflo(u) * dv);
        pk[1] = (bf16_t)(bfhi(u) * dv);
        *p = __builtin_bit_cast(unsigned, pk);
    }
}

// ---------------- fused aggregate + decode ----------------
// Block = 64 nodes; wave wv sequentially processes its 16 nodes (wv*16+i),
// writes z (f32, d_out) and a bf16 copy into ITS OWN rows of the LDS tile,
// then runs the decoder MFMA ladder on those rows (no cross-wave sync needed).
__global__ __launch_bounds__(256) void k_aggdec(const int* __restrict__ ebuf,
                                                const int* __restrict__ off,
                                                const int* __restrict__ cnt,
                                                const float* __restrict__ dinv,
                                                const unsigned* __restrict__ hb,  // scaled bf16 pairs [N][64]
                                                const float* __restrict__ benc,
                                                const bf16_t* __restrict__ wpd,
                                                const float* __restrict__ bdec,
                                                float* __restrict__ z,
                                                float* __restrict__ xrec, int n) {
    __shared__ __align__(16) bf16_t lds[64 * LDS2_STRIDE];
    const int t = threadIdx.x;
    const int wv = t >> 6, lane = t & 63;
    const int nodebase = blockIdx.x * 64 + wv * 16;

    for (int i = 0; i < 16; ++i) {
        const int node = nodebase + i;
        float acc0 = 0.f, acc1 = 0.f;
        float dc = 0.f;
        if (node < n) {
            dc = dinv[node];
            const unsigned hself = hb[(size_t)node * 64 + lane];
            acc0 = bflo(hself);
            acc1 = bfhi(hself);
            const int base = off[node], m = cnt[node];
            int j = 0;
            for (; j + 16 <= m; j += 16) {
                int r[16]; unsigned u[16];
                #pragma unroll
                for (int q = 0; q < 16; ++q) r[q] = ebuf[base + j + q];
                #pragma unroll
                for (int q = 0; q < 16; ++q) u[q] = hb[(size_t)r[q] * 64 + lane];
                #pragma unroll
                for (int q = 0; q < 16; ++q) {
                    acc0 += bflo(u[q]);
                    acc1 += bfhi(u[q]);
                }
            }
            for (; j + 4 <= m; j += 4) {
                int r[4]; unsigned u[4];
                #pragma unroll
                for (int q = 0; q < 4; ++q) r[q] = ebuf[base + j + q];
                #pragma unroll
                for (int q = 0; q < 4; ++q) u[q] = hb[(size_t)r[q] * 64 + lane];
                #pragma unroll
                for (int q = 0; q < 4; ++q) {
                    acc0 += bflo(u[q]);
                    acc1 += bfhi(u[q]);
                }
            }
            for (; j < m; ++j) {
                const unsigned u = hb[(size_t)ebuf[base + j] * 64 + lane];
                acc0 += bflo(u);
                acc1 += bfhi(u);
            }
        }
        f32x2 o;
        o[0] = fmaxf(fmaf(dc, acc0, benc[lane * 2]), 0.f);
        o[1] = fmaxf(fmaf(dc, acc1, benc[lane * 2 + 1]), 0.f);
        if (node < n)
            *reinterpret_cast<f32x2*>(&z[(size_t)node * HDIM + lane * 2]) = o;
        bf16x2 ob;
        ob[0] = (node < n) ? (bf16_t)o[0] : (bf16_t)0.f;
        ob[1] = (node < n) ? (bf16_t)o[1] : (bf16_t)0.f;
        *reinterpret_cast<bf16x2*>(&lds[(wv * 16 + i) * LDS2_STRIDE + lane * 2]) = ob;
    }

    // decoder: A-fragments come from THIS wave's 16 LDS rows
    const int fr = lane & 15, kg = lane >> 4;
    bf16x8 af[4];
    #pragma unroll
    for (int k = 0; k < 4; ++k)
        af[k] = *reinterpret_cast<const bf16x8*>(&lds[(wv * 16 + fr) * LDS2_STRIDE + k * 32 + kg * 8]);
    mfma_epi<HDIM, NDIM, false>(af, wpd, bdec, xrec, blockIdx.x, n);
}

extern "C" void kernel_launch(void* const* d_in, const int* in_sizes, int n_in,
                              void* d_out, int out_size, void* d_ws, size_t ws_size,
                              hipStream_t stream) {
    const float* x     = (const float*)d_in[0];
    const int*   ei    = (const int*)d_in[1];
    const float* W_enc = (const float*)d_in[2];
    const float* b_enc = (const float*)d_in[3];
    const float* W_dec = (const float*)d_in[4];
    const float* b_dec = (const float*)d_in[5];

    const int N = in_sizes[0] / NDIM;   // 100000
    const int E = in_sizes[1] / 2;      // 1600000
    const int* row = ei;
    const int* col = ei + E;

    const int NBKT = (N + 255) >> 8;          // buckets of 256 nodes
    const int M = NBKT * 256;                 // (bin,blk) matrix
    const int EPB = (E + 255) / 256;          // edges per P1 block
    const int G1 = (N + 63) / 64;             // GEMM/aggdec row-tile blocks
    const int SB = (M + 1023) / 1024;         // scan blocks

    // workspace layout (pbuf dead after P2; no zb needed anymore)
    char* wsp = (char*)d_ws;
    int*    pbuf = (int*)wsp;                                   // [E] packed
    const size_t r0 = (size_t)E * 4;
    bf16_t* hb   = (bf16_t*)(wsp + r0);                         // [N][HDIM] bf16
    int*    ebuf = (int*)(wsp + r0 + (size_t)N * HDIM * 2);     // [E]
    int*    goff = ebuf + E;                                    // [NPAD]
    int*    gcnt = goff + NPAD;                                 // [NPAD]
    float*  dinv = (float*)(gcnt + NPAD);                       // [NPAD]
    int*    bcnt = (int*)(dinv + NPAD);                         // [M]
    int*    bbase = bcnt + M;                                   // [M+1]
    int*    bsum = bbase + M + 1;                               // [SB pad 128]
    int*    bofs = bsum + 128;                                  // [128]
    bf16_t* wpe  = (bf16_t*)(bofs + 128);                       // packed enc weights
    bf16_t* wpd  = wpe + HDIM * NDIM;                           // packed dec weights

    float* z    = (float*)d_out;
    float* xrec = (float*)d_out + (size_t)N * HDIM;

    // 1) pack weights
    k_prep<<<32, 256, 0, stream>>>(W_enc, wpe, W_dec, wpd);

    // 2) fused: GEMM1 || P1a bucket histograms (no global atomics anywhere)
    k_fused<<<G1 + 256, 256, 0, stream>>>(x, wpe, hb, N, col, bcnt, E, NBKT, EPB, G1);

    // 3) hierarchical exclusive scan of (bin,blk) counts
    k_scanB1<<<SB, 256, 0, stream>>>(bcnt, bsum, M);
    k_scanB2<<<1, 128, 0, stream>>>(bsum, bofs, bbase, SB, M);
    k_scanB3<<<SB, 256, 0, stream>>>(bcnt, bofs, bbase, M);

    // 4) partition edges into buckets (packed entries)
    k_p1b<<<256, 256, 0, stream>>>(row, col, bbase, pbuf, E, NBKT, EPB);

    // 5) per-bucket CSR build + dinv + hb pre-scale (LDS atomics only)
    k_p2<<<NBKT, 256, 0, stream>>>(pbuf, bbase, ebuf, goff, gcnt, dinv, (unsigned*)hb, N, E);

    // 6) fused: z = relu(dc*sum(hb')+b_enc)  AND  x_recon = z_bf16 @ W_dec^T + b_dec
    k_aggdec<<<G1, 256, 0, stream>>>(ebuf, goff, gcnt, dinv, (const unsigned*)hb,
                                     b_enc, wpd, b_dec, z, xrec, N);
}

// Round 15
// 226.336 us; speedup vs baseline: 1.2193x; 1.2193x over previous
//
#include <hip/hip_runtime.h>
#include <hip/hip_bf16.h>

#define NDIM 256   // IN_DIM
#define HDIM 128   // HID
#define NPAD 100352
#define LDS1_STRIDE 264      // bf16 row stride for GEMM1 staging (256 + 8 pad)
#define LDS2_STRIDE 136      // bf16 row stride for GEMM2 staging (128 + 8 pad)
#define P2CAP 6144           // edges cached in LDS per bucket (expected ~4092)

typedef __bf16 bf16_t;
typedef bf16_t bf16x2 __attribute__((ext_vector_type(2)));
typedef bf16_t bf16x4 __attribute__((ext_vector_type(4)));
typedef bf16_t bf16x8 __attribute__((ext_vector_type(8)));
typedef float f32x2 __attribute__((ext_vector_type(2)));
typedef float f32x4 __attribute__((ext_vector_type(4)));

__device__ __forceinline__ float bflo(unsigned u) { return __uint_as_float(u << 16); }
__device__ __forceinline__ float bfhi(unsigned u) { return __uint_as_float(u & 0xffff0000u); }

// ---------------- prep body: pack both weights into MFMA fragment order ----------------
__device__ __forceinline__ void prep_body(const int b, const float* __restrict__ We, bf16_t* __restrict__ wpe,
                                          const float* __restrict__ Wd, bf16_t* __restrict__ wpd) {
    const int t = threadIdx.x;
    const bool enc = b < 16;
    const int i = (enc ? b : b - 16) * 256 + t;  // 0..4095
    const int lane = i & 63;
    const int fr = lane & 15, kg = lane >> 4;
    int nf, kk32, K, NF;
    const float* W;
    bf16_t* wp;
    if (enc) { nf = (i >> 6) & 7;  kk32 = i >> 9;  K = NDIM; NF = 8;  W = We; wp = wpe; }
    else     { nf = (i >> 6) & 15; kk32 = i >> 10; K = HDIM; NF = 16; W = Wd; wp = wpd; }
    const float* src = &W[(size_t)(nf * 16 + fr) * K + kk32 * 32 + kg * 8];
    const f32x4 a0 = *reinterpret_cast<const f32x4*>(src);
    const f32x4 a1 = *reinterpret_cast<const f32x4*>(src + 4);
    bf16x8 o;
    o[0] = (bf16_t)a0[0]; o[1] = (bf16_t)a0[1]; o[2] = (bf16_t)a0[2]; o[3] = (bf16_t)a0[3];
    o[4] = (bf16_t)a1[0]; o[5] = (bf16_t)a1[1]; o[6] = (bf16_t)a1[2]; o[7] = (bf16_t)a1[3];
    reinterpret_cast<bf16x8*>(wp)[(kk32 * NF + nf) * 64 + lane] = o;
}

// ---------------- P1a body: per-block bucket histogram (LDS only) ----------------
__device__ __forceinline__ void p1a_body(const int blk, const int* __restrict__ col,
                                         int* __restrict__ bcnt, const int E_,
                                         const int nbkt, const int epb, int* lhist) {
    const int t = threadIdx.x;
    for (int i = t; i < nbkt; i += 256) lhist[i] = 0;
    __syncthreads();
    const int base = blk * epb;
    const int cnt = min(E_ - base, epb);
    for (int i = t; i < cnt; i += 256)
        atomicAdd(&lhist[col[base + i] >> 8], 1);
    __syncthreads();
    for (int i = t; i < nbkt; i += 256)
        bcnt[i * 256 + blk] = lhist[i];     // bin-major layout
}

// ---------------- pre-kernel: weight pack (blocks 0..31) || P1a histogram (rest) ----------------
__global__ __launch_bounds__(256) void k_pre(const float* __restrict__ We, bf16_t* __restrict__ wpe,
                                             const float* __restrict__ Wd, bf16_t* __restrict__ wpd,
                                             const int* __restrict__ col, int* __restrict__ bcnt,
                                             const int E_, const int nbkt, const int epb) {
    __shared__ int lhist[512];
    const int b = blockIdx.x;
    if (b < 32) prep_body(b, We, wpe, Wd, wpd);
    else        p1a_body(b - 32, col, bcnt, E_, nbkt, epb, lhist);
}

// ---------------- MFMA ladder + epilogue (af already in regs) ----------------
// mfma_f32_16x16x32_bf16: A lane l -> row l&15, k=(l>>4)*8+j; B lane l -> col l&15,
// same k; C/D lane l reg i -> col l&15, row (l>>4)*4+i. [m89]
template<int K, int NC, bool OUT_BF16>
__device__ __forceinline__ void mfma_epi(const bf16x8* af,
                                         const bf16_t* __restrict__ Wp,
                                         const float* __restrict__ bias,
                                         void* __restrict__ Cout,
                                         const int bid, const int nrows) {
    const int lane = threadIdx.x & 63;
    const int wv = threadIdx.x >> 6;
    const int fr = lane & 15;
    const int kg = lane >> 4;
    constexpr int NF = NC / 16, NK = K / 32;

    const bf16x8* wp = reinterpret_cast<const bf16x8*>(Wp);
    f32x4 acc[NF];
    const f32x4 zero4 = {0.f, 0.f, 0.f, 0.f};
    #pragma unroll
    for (int nf = 0; nf < NF; ++nf) acc[nf] = zero4;

    #pragma unroll
    for (int k = 0; k < NK; ++k) {
        #pragma unroll
        for (int nf = 0; nf < NF; ++nf)
            acc[nf] = __builtin_amdgcn_mfma_f32_16x16x32_bf16(af[k], wp[(k * NF + nf) * 64 + lane], acc[nf], 0, 0, 0);
    }

    const long long rbase = (long long)bid * 64 + wv * 16 + kg * 4;
    #pragma unroll
    for (int nf = 0; nf < NF; ++nf) {
        const int c = nf * 16 + fr;
        const float bv = bias ? bias[c] : 0.f;
        #pragma unroll
        for (int i = 0; i < 4; ++i) {
            const long long r = rbase + i;
            if (r < nrows) {
                const float v = acc[nf][i] + bv;
                if (OUT_BF16) ((bf16_t*)Cout)[r * NC + c] = (bf16_t)v;
                else          __builtin_nontemporal_store(v, &((float*)Cout)[r * NC + c]);
            }
        }
    }
}

// ---------------- GEMM1 body: LDS-staged A (f32 -> bf16), 64 rows/block ----------------
// x loads are non-temporal (stream-once; keep L2/L3 for hb).
__device__ __forceinline__ void gemm1_body(const int bid, const float* __restrict__ x,
                                           const bf16_t* __restrict__ wpe,
                                           bf16_t* __restrict__ hb, const int nrows,
                                           bf16_t* lds) {
    const int t = threadIdx.x;
    const long long rowbase = (long long)bid * 64;
    #pragma unroll
    for (int p = 0; p < 16; ++p) {
        const int s = p * 256 + t;          // float4 slot
        const int r = s >> 6, c4 = s & 63;
        long long gr = rowbase + r;
        if (gr >= nrows) gr = nrows - 1;
        const f32x4 v = __builtin_nontemporal_load(reinterpret_cast<const f32x4*>(&x[gr * NDIM + c4 * 4]));
        bf16x4 o;
        o[0] = (bf16_t)v[0]; o[1] = (bf16_t)v[1]; o[2] = (bf16_t)v[2]; o[3] = (bf16_t)v[3];
        *reinterpret_cast<bf16x4*>(&lds[r * LDS1_STRIDE + c4 * 4]) = o;
    }
    __syncthreads();
    const int lane = t & 63, wv = t >> 6, fr = lane & 15, kg = lane >> 4;
    bf16x8 af[8];
    #pragma unroll
    for (int k = 0; k < 8; ++k)
        af[k] = *reinterpret_cast<const bf16x8*>(&lds[(wv * 16 + fr) * LDS1_STRIDE + k * 32 + kg * 8]);
    mfma_epi<NDIM, HDIM, true>(af, wpe, nullptr, hb, bid, nrows);
}

// ---------------- P1b body: partition edges into buckets (private LDS cursors) ----------------
// pbuf entry: packed  r | ((c & 255) << 17)   (r < 2^17, only col low-8 needed by P2)
__device__ __forceinline__ void p1b_body(const int blk, const int* __restrict__ row,
                                         const int* __restrict__ col,
                                         const int* __restrict__ bbase,
                                         int* __restrict__ pbuf,
                                         const int E_, const int nbkt, const int epb,
                                         int* lcur) {
    const int t = threadIdx.x;
    for (int i = t; i < nbkt; i += 256) lcur[i] = bbase[i * 256 + blk];
    __syncthreads();
    const int base = blk * epb;
    const int cnt = min(E_ - base, epb);
    for (int i = t; i < cnt; i += 256) {
        const int c = col[base + i];
        const int r = row[base + i];
        const int pos = atomicAdd(&lcur[c >> 8], 1);
        pbuf[pos] = r | ((c & 255) << 17);
    }
}

// ---------------- fused: GEMM1 (blocks < G1) + P1b (rest) ----------------
__global__ __launch_bounds__(256) void k_fused(const float* __restrict__ x,
                                               const bf16_t* __restrict__ wpe,
                                               bf16_t* __restrict__ hb, const int nrows,
                                               const int* __restrict__ row,
                                               const int* __restrict__ col,
                                               const int* __restrict__ bbase,
                                               int* __restrict__ pbuf,
                                               const int E_, const int nbkt, const int epb,
                                               const int G1) {
    __shared__ __align__(16) bf16_t lds[64 * LDS1_STRIDE];
    const int b = blockIdx.x;
    if (b < G1) gemm1_body(b, x, wpe, hb, nrows, lds);
    else        p1b_body(b - G1, row, col, bbase, pbuf, E_, nbkt, epb, (int*)lds);
}

// ---------------- hierarchical exclusive scan over bcnt[M] (3 passes) ----------------
__global__ __launch_bounds__(256) void k_scanB1(const int* __restrict__ bcnt,
                                                int* __restrict__ bsum, const int M) {
    __shared__ int s[256];
    const int b = blockIdx.x, t = threadIdx.x;
    const int i0 = b * 1024 + t * 4;
    int4 v = make_int4(0, 0, 0, 0);
    if (i0 + 4 <= M) v = *reinterpret_cast<const int4*>(&bcnt[i0]);
    else if (i0 < M) {
        const int k = M - i0;
        v.x = bcnt[i0];
        if (k > 1) v.y = bcnt[i0 + 1];
        if (k > 2) v.z = bcnt[i0 + 2];
    }
    s[t] = v.x + v.y + v.z + v.w;
    __syncthreads();
    for (int d = 128; d > 0; d >>= 1) {
        if (t < d) s[t] += s[t + d];
        __syncthreads();
    }
    if (t == 0) bsum[b] = s[0];
}

__global__ __launch_bounds__(128) void k_scanB2(const int* __restrict__ bsum,
                                                int* __restrict__ bofs,
                                                int* __restrict__ bbase,
                                                const int nb, const int M) {
    __shared__ int s[128];
    const int t = threadIdx.x;
    const int v = (t < nb) ? bsum[t] : 0;
    s[t] = v;
    __syncthreads();
    for (int d = 1; d < 128; d <<= 1) {
        int xx = (t >= d) ? s[t - d] : 0;
        __syncthreads();
        s[t] += xx;
        __syncthreads();
    }
    if (t < nb) bofs[t] = s[t] - v;      // exclusive
    if (t == nb - 1) bbase[M] = s[t];    // total = E
}

__global__ __launch_bounds__(256) void k_scanB3(const int* __restrict__ bcnt,
                                                const int* __restrict__ bofs,
                                                int* __restrict__ bbase, const int M) {
    __shared__ int s[256];
    const int b = blockIdx.x, t = threadIdx.x;
    const int i0 = b * 1024 + t * 4;
    int4 v = make_int4(0, 0, 0, 0);
    if (i0 + 4 <= M) v = *reinterpret_cast<const int4*>(&bcnt[i0]);
    else if (i0 < M) {
        const int k = M - i0;
        v.x = bcnt[i0];
        if (k > 1) v.y = bcnt[i0 + 1];
        if (k > 2) v.z = bcnt[i0 + 2];
    }
    const int tsum = v.x + v.y + v.z + v.w;
    s[t] = tsum;
    __syncthreads();
    for (int d = 1; d < 256; d <<= 1) {
        int xx = (t >= d) ? s[t - d] : 0;
        __syncthreads();
        s[t] += xx;
        __syncthreads();
    }
    const int excl = s[t] - tsum + bofs[b];
    int4 o;
    o.x = excl; o.y = excl + v.x; o.z = o.y + v.y; o.w = o.z + v.z;
    if (i0 + 4 <= M) *reinterpret_cast<int4*>(&bbase[i0]) = o;
    else if (i0 < M) {
        const int k = M - i0;
        bbase[i0] = o.x;
        if (k > 1) bbase[i0 + 1] = o.y;
        if (k > 2) bbase[i0 + 2] = o.z;
    }
}

// ---------------- P2: per-bucket CSR build + dinv + pre-scale hb rows by dinv ----------------
__global__ __launch_bounds__(256) void k_p2(const int* __restrict__ pbuf,
                                            const int* __restrict__ bbase,
                                            int* __restrict__ ebuf,
                                            int* __restrict__ goff, int* __restrict__ gcnt,
                                            float* __restrict__ dinv,
                                            unsigned* __restrict__ hbw,   // [N][64] bf16-pairs, scaled in place
                                            const int n, const int E_) {
    __shared__ int lcnt[256], lscan[256], lcur[256];
    __shared__ float ldinv[256];
    __shared__ __align__(16) int ecache[P2CAP];
    const int b = blockIdx.x, t = threadIdx.x;
    const int start = bbase[b * 256];
    const int end = bbase[(b + 1) * 256];
    const int size = end - start;
    const bool inlds = size <= P2CAP;
    lcnt[t] = 0; lcur[t] = 0;
    __syncthreads();
    if (inlds) {
        for (int i = t; i < size; i += 256) {
            const int e = pbuf[start + i];
            ecache[i] = e;
            atomicAdd(&lcnt[(e >> 17) & 255], 1);
        }
    } else {
        for (int i = t; i < size; i += 256)
            atomicAdd(&lcnt[(pbuf[start + i] >> 17) & 255], 1);
    }
    __syncthreads();
    const int v = lcnt[t];
    lscan[t] = v;
    __syncthreads();
    for (int d = 1; d < 256; d <<= 1) {
        int xx = (t >= d) ? lscan[t - d] : 0;
        __syncthreads();
        lscan[t] += xx;
        __syncthreads();
    }
    const int excl = lscan[t] - v;
    const int node = (b << 8) + t;
    float dvv = 0.f;
    if (node < n) {
        dvv = rsqrtf((float)(v + 1));
        goff[node] = start + excl;
        gcnt[node] = v;
        dinv[node] = dvv;
    }
    ldinv[t] = dvv;
    lscan[t] = excl;
    __syncthreads();
    for (int i = t; i < size; i += 256) {
        const int e = inlds ? ecache[i] : pbuf[start + i];
        const int li = (e >> 17) & 255;
        const int rk = atomicAdd(&lcur[li], 1);
        ebuf[start + lscan[li] + rk] = e & 0x1FFFF;
    }
    // pre-scale hb rows of this bucket: hb'[node] = hb[node] * dinv[node]
    const int wv = t >> 6, lane = t & 63;
    #pragma unroll 4
    for (int rr = wv * 64; rr < wv * 64 + 64; ++rr) {
        const int nd = (b << 8) + rr;
        if (nd >= n) break;
        const float dv = ldinv[rr];
        unsigned* p = &hbw[(size_t)nd * 64 + lane];
        const unsigned u = *p;
        bf16x2 pk;
        pk[0] = (bf16_t)(bflo(u) * dv);
        pk[1] = (bf16_t)(bfhi(u) * dv);
        *p = __builtin_bit_cast(unsigned, pk);
    }
}

// ---------------- gather-aggregate + self-loop + bias + relu (+ bf16 copy of z) ----------------
// hb rows pre-scaled by dinv[src] -> inner loop is pure adds; final z = dc * acc + b.
// 1 wave per node; lane = 2 features (uint = 2 bf16); 16-deep gather unroll.
__global__ __launch_bounds__(256) void k_agg(const int* __restrict__ ebuf,
                                             const int* __restrict__ off,
                                             const int* __restrict__ cnt,
                                             const float* __restrict__ dinv,
                                             const unsigned* __restrict__ hb,  // scaled bf16 pairs [N][64]
                                             const float* __restrict__ benc,
                                             float* __restrict__ z,
                                             bf16_t* __restrict__ zb, int n) {
    const int node = blockIdx.x * 4 + (threadIdx.x >> 6);
    const int lane = threadIdx.x & 63;
    if (node >= n) return;
    const float dc = dinv[node];
    const unsigned hself = hb[(size_t)node * 64 + lane];
    float acc0 = bflo(hself);
    float acc1 = bfhi(hself);
    const int base = off[node], m = cnt[node];
    int j = 0;
    for (; j + 16 <= m; j += 16) {
        int r[16]; unsigned u[16];
        #pragma unroll
        for (int q = 0; q < 16; ++q) r[q] = ebuf[base + j + q];
        #pragma unroll
        for (int q = 0; q < 16; ++q) u[q] = hb[(size_t)r[q] * 64 + lane];
        #pragma unroll
        for (int q = 0; q < 16; ++q) {
            acc0 += bflo(u[q]);
            acc1 += bfhi(u[q]);
        }
    }
    for (; j + 4 <= m; j += 4) {
        int r[4]; unsigned u[4];
        #pragma unroll
        for (int q = 0; q < 4; ++q) r[q] = ebuf[base + j + q];
        #pragma unroll
        for (int q = 0; q < 4; ++q) u[q] = hb[(size_t)r[q] * 64 + lane];
        #pragma unroll
        for (int q = 0; q < 4; ++q) {
            acc0 += bflo(u[q]);
            acc1 += bfhi(u[q]);
        }
    }
    for (; j < m; ++j) {
        const unsigned u = hb[(size_t)ebuf[base + j] * 64 + lane];
        acc0 += bflo(u);
        acc1 += bfhi(u);
    }
    f32x2 o;
    o[0] = fmaxf(fmaf(dc, acc0, benc[lane * 2]), 0.f);
    o[1] = fmaxf(fmaf(dc, acc1, benc[lane * 2 + 1]), 0.f);
    *reinterpret_cast<f32x2*>(&z[(size_t)node * HDIM + lane * 2]) = o;
    bf16x2 ob;
    ob[0] = (bf16_t)o[0];
    ob[1] = (bf16_t)o[1];
    *reinterpret_cast<bf16x2*>(&zb[(size_t)node * HDIM + lane * 2]) = ob;
}

// ---------------- GEMM2: LDS-staged A (bf16), 64 rows/block ----------------
__global__ __launch_bounds__(256) void k_gemm2(const bf16_t* __restrict__ zb,
                                               const bf16_t* __restrict__ wpd,
                                               const float* __restrict__ bias,
                                               float* __restrict__ xrec, const int nrows) {
    __shared__ __align__(16) bf16_t lds[64 * LDS2_STRIDE];
    const int t = threadIdx.x;
    const long long rowbase = (long long)blockIdx.x * 64;
    #pragma unroll
    for (int p = 0; p < 4; ++p) {
        const int s = p * 256 + t;       // bf16x8 slot
        const int r = s >> 4, c8 = s & 15;
        long long gr = rowbase + r;
        if (gr >= nrows) gr = nrows - 1;
        const bf16x8 v = *reinterpret_cast<const bf16x8*>(&zb[gr * HDIM + c8 * 8]);
        *reinterpret_cast<bf16x8*>(&lds[r * LDS2_STRIDE + c8 * 8]) = v;
    }
    __syncthreads();
    const int lane = t & 63, wv = t >> 6, fr = lane & 15, kg = lane >> 4;
    bf16x8 af[4];
    #pragma unroll
    for (int k = 0; k < 4; ++k)
        af[k] = *reinterpret_cast<const bf16x8*>(&lds[(wv * 16 + fr) * LDS2_STRIDE + k * 32 + kg * 8]);
    mfma_epi<HDIM, NDIM, false>(af, wpd, bias, xrec, blockIdx.x, nrows);
}

extern "C" void kernel_launch(void* const* d_in, const int* in_sizes, int n_in,
                              void* d_out, int out_size, void* d_ws, size_t ws_size,
                              hipStream_t stream) {
    const float* x     = (const float*)d_in[0];
    const int*   ei    = (const int*)d_in[1];
    const float* W_enc = (const float*)d_in[2];
    const float* b_enc = (const float*)d_in[3];
    const float* W_dec = (const float*)d_in[4];
    const float* b_dec = (const float*)d_in[5];

    const int N = in_sizes[0] / NDIM;   // 100000
    const int E = in_sizes[1] / 2;      // 1600000
    const int* row = ei;
    const int* col = ei + E;

    const int NBKT = (N + 255) >> 8;          // buckets of 256 nodes
    const int M = NBKT * 256;                 // (bin,blk) matrix
    const int EPB = (E + 255) / 256;          // edges per P1 block
    const int G1 = (N + 63) / 64;             // GEMM row-tile blocks
    const int SB = (M + 1023) / 1024;         // scan blocks

    // workspace layout: region 0 time-shared (pbuf during P1b/P2; zb during agg/gemm2)
    char* wsp = (char*)d_ws;
    int*    pbuf = (int*)wsp;                                   // [E] packed
    bf16_t* zb   = (bf16_t*)wsp;                                // [N][HDIM] bf16
    const size_t r0 = ((size_t)N * HDIM * 2 > (size_t)E * 4) ? (size_t)N * HDIM * 2 : (size_t)E * 4;
    bf16_t* hb   = (bf16_t*)(wsp + r0);                         // [N][HDIM] bf16
    int*    ebuf = (int*)(wsp + r0 + (size_t)N * HDIM * 2);     // [E]
    int*    goff = ebuf + E;                                    // [NPAD]
    int*    gcnt = goff + NPAD;                                 // [NPAD]
    float*  dinv = (float*)(gcnt + NPAD);                       // [NPAD]
    int*    bcnt = (int*)(dinv + NPAD);                         // [M]
    int*    bbase = bcnt + M;                                   // [M+1]
    int*    bsum = bbase + M + 1;                               // [SB pad 128]
    int*    bofs = bsum + 128;                                  // [128]
    bf16_t* wpe  = (bf16_t*)(bofs + 128);                       // packed enc weights
    bf16_t* wpd  = wpe + HDIM * NDIM;                           // packed dec weights

    float* z    = (float*)d_out;
    float* xrec = (float*)d_out + (size_t)N * HDIM;

    // 1) pack weights (blocks 0..31) || P1a bucket histograms (blocks 32..287)
    k_pre<<<32 + 256, 256, 0, stream>>>(W_enc, wpe, W_dec, wpd, col, bcnt, E, NBKT, EPB);

    // 2) hierarchical exclusive scan of (bin,blk) counts
    k_scanB1<<<SB, 256, 0, stream>>>(bcnt, bsum, M);
    k_scanB2<<<1, 128, 0, stream>>>(bsum, bofs, bbase, SB, M);
    k_scanB3<<<SB, 256, 0, stream>>>(bcnt, bofs, bbase, M);

    // 3) fused: GEMM1 (h = bf16(x @ W_enc^T)) || P1b edge partition
    k_fused<<<G1 + 256, 256, 0, stream>>>(x, wpe, hb, N, row, col, bbase, pbuf, E, NBKT, EPB, G1);

    // 4) per-bucket CSR build + dinv + hb pre-scale (LDS atomics only)
    k_p2<<<NBKT, 256, 0, stream>>>(pbuf, bbase, ebuf, goff, gcnt, dinv, (unsigned*)hb, N, E);

    // 5) z = relu(dc * sum(hb') + b_enc)  (+ bf16 copy zb; pbuf dead now)
    k_agg<<<(N + 3) / 4, 256, 0, stream>>>(ebuf, goff, gcnt, dinv, (const unsigned*)hb, b_enc, z, zb, N);

    // 6) x_recon = zb @ W_dec^T + b_dec
    k_gemm2<<<G1, 256, 0, stream>>>(zb, wpd, b_dec, xrec, N);
}

// Round 16
// 223.895 us; speedup vs baseline: 1.2326x; 1.0109x over previous
//
#include <hip/hip_runtime.h>
#include <hip/hip_bf16.h>

#define NDIM 256   // IN_DIM
#define HDIM 128   // HID
#define NPAD 100352
#define LDS1_STRIDE 264      // bf16 row stride for GEMM1 staging (256 + 8 pad)
#define LDS2_STRIDE 136      // bf16 row stride for GEMM2 staging (128 + 8 pad)
#define P2CAP 6144           // edges cached in LDS per bucket (expected ~4092)

typedef __bf16 bf16_t;
typedef bf16_t bf16x2 __attribute__((ext_vector_type(2)));
typedef bf16_t bf16x4 __attribute__((ext_vector_type(4)));
typedef bf16_t bf16x8 __attribute__((ext_vector_type(8)));
typedef float f32x2 __attribute__((ext_vector_type(2)));
typedef float f32x4 __attribute__((ext_vector_type(4)));

__device__ __forceinline__ float bflo(unsigned u) { return __uint_as_float(u << 16); }
__device__ __forceinline__ float bfhi(unsigned u) { return __uint_as_float(u & 0xffff0000u); }

// ---------------- prep: pack both weights into MFMA fragment order ----------------
__global__ __launch_bounds__(256) void k_prep(const float* __restrict__ We, bf16_t* __restrict__ wpe,
                                              const float* __restrict__ Wd, bf16_t* __restrict__ wpd) {
    const int b = blockIdx.x, t = threadIdx.x;
    const bool enc = b < 16;
    const int i = (enc ? b : b - 16) * 256 + t;  // 0..4095
    const int lane = i & 63;
    const int fr = lane & 15, kg = lane >> 4;
    int nf, kk32, K, NF;
    const float* W;
    bf16_t* wp;
    if (enc) { nf = (i >> 6) & 7;  kk32 = i >> 9;  K = NDIM; NF = 8;  W = We; wp = wpe; }
    else     { nf = (i >> 6) & 15; kk32 = i >> 10; K = HDIM; NF = 16; W = Wd; wp = wpd; }
    const float* src = &W[(size_t)(nf * 16 + fr) * K + kk32 * 32 + kg * 8];
    const f32x4 a0 = *reinterpret_cast<const f32x4*>(src);
    const f32x4 a1 = *reinterpret_cast<const f32x4*>(src + 4);
    bf16x8 o;
    o[0] = (bf16_t)a0[0]; o[1] = (bf16_t)a0[1]; o[2] = (bf16_t)a0[2]; o[3] = (bf16_t)a0[3];
    o[4] = (bf16_t)a1[0]; o[5] = (bf16_t)a1[1]; o[6] = (bf16_t)a1[2]; o[7] = (bf16_t)a1[3];
    reinterpret_cast<bf16x8*>(wp)[(kk32 * NF + nf) * 64 + lane] = o;
}

// ---------------- MFMA ladder + epilogue (af already in regs) ----------------
// mfma_f32_16x16x32_bf16: A lane l -> row l&15, k=(l>>4)*8+j; B lane l -> col l&15,
// same k; C/D lane l reg i -> col l&15, row (l>>4)*4+i. [m89]
// f32-output path (xrec) uses non-temporal stores: output is never re-read.
template<int K, int NC, bool OUT_BF16>
__device__ __forceinline__ void mfma_epi(const bf16x8* af,
                                         const bf16_t* __restrict__ Wp,
                                         const float* __restrict__ bias,
                                         void* __restrict__ Cout,
                                         const int bid, const int nrows) {
    const int lane = threadIdx.x & 63;
    const int wv = threadIdx.x >> 6;
    const int fr = lane & 15;
    const int kg = lane >> 4;
    constexpr int NF = NC / 16, NK = K / 32;

    const bf16x8* wp = reinterpret_cast<const bf16x8*>(Wp);
    f32x4 acc[NF];
    const f32x4 zero4 = {0.f, 0.f, 0.f, 0.f};
    #pragma unroll
    for (int nf = 0; nf < NF; ++nf) acc[nf] = zero4;

    #pragma unroll
    for (int k = 0; k < NK; ++k) {
        #pragma unroll
        for (int nf = 0; nf < NF; ++nf)
            acc[nf] = __builtin_amdgcn_mfma_f32_16x16x32_bf16(af[k], wp[(k * NF + nf) * 64 + lane], acc[nf], 0, 0, 0);
    }

    const long long rbase = (long long)bid * 64 + wv * 16 + kg * 4;
    #pragma unroll
    for (int nf = 0; nf < NF; ++nf) {
        const int c = nf * 16 + fr;
        const float bv = bias ? bias[c] : 0.f;
        #pragma unroll
        for (int i = 0; i < 4; ++i) {
            const long long r = rbase + i;
            if (r < nrows) {
                const float v = acc[nf][i] + bv;
                if (OUT_BF16) ((bf16_t*)Cout)[r * NC + c] = (bf16_t)v;
                else          __builtin_nontemporal_store(v, &((float*)Cout)[r * NC + c]);
            }
        }
    }
}

// ---------------- GEMM1 body: LDS-staged A (f32 -> bf16), 64 rows/block ----------------
// x loads are non-temporal (stream-once; keep L2/L3 for hb).
__device__ __forceinline__ void gemm1_body(const int bid, const float* __restrict__ x,
                                           const bf16_t* __restrict__ wpe,
                                           bf16_t* __restrict__ hb, const int nrows,
                                           bf16_t* lds) {
    const int t = threadIdx.x;
    const long long rowbase = (long long)bid * 64;
    #pragma unroll
    for (int p = 0; p < 16; ++p) {
        const int s = p * 256 + t;          // float4 slot
        const int r = s >> 6, c4 = s & 63;
        long long gr = rowbase + r;
        if (gr >= nrows) gr = nrows - 1;
        const f32x4 v = __builtin_nontemporal_load(reinterpret_cast<const f32x4*>(&x[gr * NDIM + c4 * 4]));
        bf16x4 o;
        o[0] = (bf16_t)v[0]; o[1] = (bf16_t)v[1]; o[2] = (bf16_t)v[2]; o[3] = (bf16_t)v[3];
        *reinterpret_cast<bf16x4*>(&lds[r * LDS1_STRIDE + c4 * 4]) = o;
    }
    __syncthreads();
    const int lane = t & 63, wv = t >> 6, fr = lane & 15, kg = lane >> 4;
    bf16x8 af[8];
    #pragma unroll
    for (int k = 0; k < 8; ++k)
        af[k] = *reinterpret_cast<const bf16x8*>(&lds[(wv * 16 + fr) * LDS1_STRIDE + k * 32 + kg * 8]);
    mfma_epi<NDIM, HDIM, true>(af, wpe, nullptr, hb, bid, nrows);
}

// ---------------- P1a body: per-block bucket histogram (LDS only) ----------------
__device__ __forceinline__ void p1a_body(const int blk, const int* __restrict__ col,
                                         int* __restrict__ bcnt, const int E_,
                                         const int nbkt, const int epb, int* lhist) {
    const int t = threadIdx.x;
    for (int i = t; i < nbkt; i += 256) lhist[i] = 0;
    __syncthreads();
    const int base = blk * epb;
    const int cnt = min(E_ - base, epb);
    for (int i = t; i < cnt; i += 256)
        atomicAdd(&lhist[col[base + i] >> 8], 1);
    __syncthreads();
    for (int i = t; i < nbkt; i += 256)
        bcnt[i * 256 + blk] = lhist[i];     // bin-major layout
}

// ---------------- fused: GEMM1 (blocks < G1) + P1a (rest) ----------------
__global__ __launch_bounds__(256) void k_fused(const float* __restrict__ x,
                                               const bf16_t* __restrict__ wpe,
                                               bf16_t* __restrict__ hb, const int nrows,
                                               const int* __restrict__ col,
                                               int* __restrict__ bcnt,
                                               const int E_, const int nbkt, const int epb,
                                               const int G1) {
    __shared__ __align__(16) bf16_t lds[64 * LDS1_STRIDE];
    const int b = blockIdx.x;
    if (b < G1) gemm1_body(b, x, wpe, hb, nrows, lds);
    else        p1a_body(b - G1, col, bcnt, E_, nbkt, epb, (int*)lds);
}

// ---------------- hierarchical exclusive scan over bcnt[M] (3 passes) ----------------
__global__ __launch_bounds__(256) void k_scanB1(const int* __restrict__ bcnt,
                                                int* __restrict__ bsum, const int M) {
    __shared__ int s[256];
    const int b = blockIdx.x, t = threadIdx.x;
    const int i0 = b * 1024 + t * 4;
    int4 v = make_int4(0, 0, 0, 0);
    if (i0 + 4 <= M) v = *reinterpret_cast<const int4*>(&bcnt[i0]);
    else if (i0 < M) {
        const int k = M - i0;
        v.x = bcnt[i0];
        if (k > 1) v.y = bcnt[i0 + 1];
        if (k > 2) v.z = bcnt[i0 + 2];
    }
    s[t] = v.x + v.y + v.z + v.w;
    __syncthreads();
    for (int d = 128; d > 0; d >>= 1) {
        if (t < d) s[t] += s[t + d];
        __syncthreads();
    }
    if (t == 0) bsum[b] = s[0];
}

__global__ __launch_bounds__(128) void k_scanB2(const int* __restrict__ bsum,
                                                int* __restrict__ bofs,
                                                int* __restrict__ bbase,
                                                const int nb, const int M) {
    __shared__ int s[128];
    const int t = threadIdx.x;
    const int v = (t < nb) ? bsum[t] : 0;
    s[t] = v;
    __syncthreads();
    for (int d = 1; d < 128; d <<= 1) {
        int xx = (t >= d) ? s[t - d] : 0;
        __syncthreads();
        s[t] += xx;
        __syncthreads();
    }
    if (t < nb) bofs[t] = s[t] - v;      // exclusive
    if (t == nb - 1) bbase[M] = s[t];    // total = E
}

__global__ __launch_bounds__(256) void k_scanB3(const int* __restrict__ bcnt,
                                                const int* __restrict__ bofs,
                                                int* __restrict__ bbase, const int M) {
    __shared__ int s[256];
    const int b = blockIdx.x, t = threadIdx.x;
    const int i0 = b * 1024 + t * 4;
    int4 v = make_int4(0, 0, 0, 0);
    if (i0 + 4 <= M) v = *reinterpret_cast<const int4*>(&bcnt[i0]);
    else if (i0 < M) {
        const int k = M - i0;
        v.x = bcnt[i0];
        if (k > 1) v.y = bcnt[i0 + 1];
        if (k > 2) v.z = bcnt[i0 + 2];
    }
    const int tsum = v.x + v.y + v.z + v.w;
    s[t] = tsum;
    __syncthreads();
    for (int d = 1; d < 256; d <<= 1) {
        int xx = (t >= d) ? s[t - d] : 0;
        __syncthreads();
        s[t] += xx;
        __syncthreads();
    }
    const int excl = s[t] - tsum + bofs[b];
    int4 o;
    o.x = excl; o.y = excl + v.x; o.z = o.y + v.y; o.w = o.z + v.z;
    if (i0 + 4 <= M) *reinterpret_cast<int4*>(&bbase[i0]) = o;
    else if (i0 < M) {
        const int k = M - i0;
        bbase[i0] = o.x;
        if (k > 1) bbase[i0 + 1] = o.y;
        if (k > 2) bbase[i0 + 2] = o.z;
    }
}

// ---------------- P1b: partition edges into buckets (private LDS cursors) ----------------
// pbuf entry: packed  r | ((c & 255) << 17)   (r < 2^17, only col low-8 needed by P2)
__global__ __launch_bounds__(256) void k_p1b(const int* __restrict__ row,
                                             const int* __restrict__ col,
                                             const int* __restrict__ bbase,
                                             int* __restrict__ pbuf,
                                             const int E_, const int nbkt, const int epb) {
    __shared__ int lcur[512];
    const int blk = blockIdx.x, t = threadIdx.x;
    for (int i = t; i < nbkt; i += 256) lcur[i] = bbase[i * 256 + blk];
    __syncthreads();
    const int base = blk * epb;
    const int cnt = min(E_ - base, epb);
    for (int i = t; i < cnt; i += 256) {
        const int c = col[base + i];
        const int r = row[base + i];
        const int pos = atomicAdd(&lcur[c >> 8], 1);
        pbuf[pos] = r | ((c & 255) << 17);
    }
}

// ---------------- P2: per-bucket CSR build + dinv + pre-scale hb rows by dinv ----------------
__global__ __launch_bounds__(256) void k_p2(const int* __restrict__ pbuf,
                                            const int* __restrict__ bbase,
                                            int* __restrict__ ebuf,
                                            int* __restrict__ goff, int* __restrict__ gcnt,
                                            float* __restrict__ dinv,
                                            unsigned* __restrict__ hbw,   // [N][64] bf16-pairs, scaled in place
                                            const int n, const int E_) {
    __shared__ int lcnt[256], lscan[256], lcur[256];
    __shared__ float ldinv[256];
    __shared__ __align__(16) int ecache[P2CAP];
    const int b = blockIdx.x, t = threadIdx.x;
    const int start = bbase[b * 256];
    const int end = bbase[(b + 1) * 256];
    const int size = end - start;
    const bool inlds = size <= P2CAP;
    lcnt[t] = 0; lcur[t] = 0;
    __syncthreads();
    if (inlds) {
        for (int i = t; i < size; i += 256) {
            const int e = pbuf[start + i];
            ecache[i] = e;
            atomicAdd(&lcnt[(e >> 17) & 255], 1);
        }
    } else {
        for (int i = t; i < size; i += 256)
            atomicAdd(&lcnt[(pbuf[start + i] >> 17) & 255], 1);
    }
    __syncthreads();
    const int v = lcnt[t];
    lscan[t] = v;
    __syncthreads();
    for (int d = 1; d < 256; d <<= 1) {
        int xx = (t >= d) ? lscan[t - d] : 0;
        __syncthreads();
        lscan[t] += xx;
        __syncthreads();
    }
    const int excl = lscan[t] - v;
    const int node = (b << 8) + t;
    float dvv = 0.f;
    if (node < n) {
        dvv = rsqrtf((float)(v + 1));
        goff[node] = start + excl;
        gcnt[node] = v;
        dinv[node] = dvv;
    }
    ldinv[t] = dvv;
    lscan[t] = excl;
    __syncthreads();
    for (int i = t; i < size; i += 256) {
        const int e = inlds ? ecache[i] : pbuf[start + i];
        const int li = (e >> 17) & 255;
        const int rk = atomicAdd(&lcur[li], 1);
        ebuf[start + lscan[li] + rk] = e & 0x1FFFF;
    }
    // pre-scale hb rows of this bucket: hb'[node] = hb[node] * dinv[node]
    const int wv = t >> 6, lane = t & 63;
    #pragma unroll 4
    for (int rr = wv * 64; rr < wv * 64 + 64; ++rr) {
        const int nd = (b << 8) + rr;
        if (nd >= n) break;
        const float dv = ldinv[rr];
        unsigned* p = &hbw[(size_t)nd * 64 + lane];
        const unsigned u = *p;
        bf16x2 pk;
        pk[0] = (bf16_t)(bflo(u) * dv);
        pk[1] = (bf16_t)(bfhi(u) * dv);
        *p = __builtin_bit_cast(unsigned, pk);
    }
}

// ---------------- gather-aggregate + self-loop + bias + relu (+ bf16 copy of z) ----------------
// hb rows pre-scaled by dinv[src] -> inner loop is pure adds; final z = dc * acc + b.
// 1 wave per node; lane = 2 features (uint = 2 bf16); 16-deep gather unroll.
__global__ __launch_bounds__(256) void k_agg(const int* __restrict__ ebuf,
                                             const int* __restrict__ off,
                                             const int* __restrict__ cnt,
                                             const float* __restrict__ dinv,
                                             const unsigned* __restrict__ hb,  // scaled bf16 pairs [N][64]
                                             const float* __restrict__ benc,
                                             float* __restrict__ z,
                                             bf16_t* __restrict__ zb, int n) {
    const int node = blockIdx.x * 4 + (threadIdx.x >> 6);
    const int lane = threadIdx.x & 63;
    if (node >= n) return;
    const float dc = dinv[node];
    const unsigned hself = hb[(size_t)node * 64 + lane];
    float acc0 = bflo(hself);
    float acc1 = bfhi(hself);
    const int base = off[node], m = cnt[node];
    int j = 0;
    for (; j + 16 <= m; j += 16) {
        int r[16]; unsigned u[16];
        #pragma unroll
        for (int q = 0; q < 16; ++q) r[q] = ebuf[base + j + q];
        #pragma unroll
        for (int q = 0; q < 16; ++q) u[q] = hb[(size_t)r[q] * 64 + lane];
        #pragma unroll
        for (int q = 0; q < 16; ++q) {
            acc0 += bflo(u[q]);
            acc1 += bfhi(u[q]);
        }
    }
    for (; j + 4 <= m; j += 4) {
        int r[4]; unsigned u[4];
        #pragma unroll
        for (int q = 0; q < 4; ++q) r[q] = ebuf[base + j + q];
        #pragma unroll
        for (int q = 0; q < 4; ++q) u[q] = hb[(size_t)r[q] * 64 + lane];
        #pragma unroll
        for (int q = 0; q < 4; ++q) {
            acc0 += bflo(u[q]);
            acc1 += bfhi(u[q]);
        }
    }
    for (; j < m; ++j) {
        const unsigned u = hb[(size_t)ebuf[base + j] * 64 + lane];
        acc0 += bflo(u);
        acc1 += bfhi(u);
    }
    f32x2 o;
    o[0] = fmaxf(fmaf(dc, acc0, benc[lane * 2]), 0.f);
    o[1] = fmaxf(fmaf(dc, acc1, benc[lane * 2 + 1]), 0.f);
    *reinterpret_cast<f32x2*>(&z[(size_t)node * HDIM + lane * 2]) = o;
    bf16x2 ob;
    ob[0] = (bf16_t)o[0];
    ob[1] = (bf16_t)o[1];
    *reinterpret_cast<bf16x2*>(&zb[(size_t)node * HDIM + lane * 2]) = ob;
}

// ---------------- GEMM2: LDS-staged A (bf16), 64 rows/block ----------------
__global__ __launch_bounds__(256) void k_gemm2(const bf16_t* __restrict__ zb,
                                               const bf16_t* __restrict__ wpd,
                                               const float* __restrict__ bias,
                                               float* __restrict__ xrec, const int nrows) {
    __shared__ __align__(16) bf16_t lds[64 * LDS2_STRIDE];
    const int t = threadIdx.x;
    const long long rowbase = (long long)blockIdx.x * 64;
    #pragma unroll
    for (int p = 0; p < 4; ++p) {
        const int s = p * 256 + t;       // bf16x8 slot
        const int r = s >> 4, c8 = s & 15;
        long long gr = rowbase + r;
        if (gr >= nrows) gr = nrows - 1;
        const bf16x8 v = *reinterpret_cast<const bf16x8*>(&zb[gr * HDIM + c8 * 8]);
        *reinterpret_cast<bf16x8*>(&lds[r * LDS2_STRIDE + c8 * 8]) = v;
    }
    __syncthreads();
    const int lane = t & 63, wv = t >> 6, fr = lane & 15, kg = lane >> 4;
    bf16x8 af[4];
    #pragma unroll
    for (int k = 0; k < 4; ++k)
        af[k] = *reinterpret_cast<const bf16x8*>(&lds[(wv * 16 + fr) * LDS2_STRIDE + k * 32 + kg * 8]);
    mfma_epi<HDIM, NDIM, false>(af, wpd, bias, xrec, blockIdx.x, nrows);
}

extern "C" void kernel_launch(void* const* d_in, const int* in_sizes, int n_in,
                              void* d_out, int out_size, void* d_ws, size_t ws_size,
                              hipStream_t stream) {
    const float* x     = (const float*)d_in[0];
    const int*   ei    = (const int*)d_in[1];
    const float* W_enc = (const float*)d_in[2];
    const float* b_enc = (const float*)d_in[3];
    const float* W_dec = (const float*)d_in[4];
    const float* b_dec = (const float*)d_in[5];

    const int N = in_sizes[0] / NDIM;   // 100000
    const int E = in_sizes[1] / 2;      // 1600000
    const int* row = ei;
    const int* col = ei + E;

    const int NBKT = (N + 255) >> 8;          // buckets of 256 nodes
    const int M = NBKT * 256;                 // (bin,blk) matrix
    const int EPB = (E + 255) / 256;          // edges per P1 block
    const int G1 = (N + 63) / 64;             // GEMM row-tile blocks
    const int SB = (M + 1023) / 1024;         // scan blocks

    // workspace layout: region 0 time-shared (pbuf during P1b/P2; zb during agg/gemm2)
    char* wsp = (char*)d_ws;
    int*    pbuf = (int*)wsp;                                   // [E] packed
    bf16_t* zb   = (bf16_t*)wsp;                                // [N][HDIM] bf16
    const size_t r0 = ((size_t)N * HDIM * 2 > (size_t)E * 4) ? (size_t)N * HDIM * 2 : (size_t)E * 4;
    bf16_t* hb   = (bf16_t*)(wsp + r0);                         // [N][HDIM] bf16
    int*    ebuf = (int*)(wsp + r0 + (size_t)N * HDIM * 2);     // [E]
    int*    goff = ebuf + E;                                    // [NPAD]
    int*    gcnt = goff + NPAD;                                 // [NPAD]
    float*  dinv = (float*)(gcnt + NPAD);                       // [NPAD]
    int*    bcnt = (int*)(dinv + NPAD);                         // [M]
    int*    bbase = bcnt + M;                                   // [M+1]
    int*    bsum = bbase + M + 1;                               // [SB pad 128]
    int*    bofs = bsum + 128;                                  // [128]
    bf16_t* wpe  = (bf16_t*)(bofs + 128);                       // packed enc weights
    bf16_t* wpd  = wpe + HDIM * NDIM;                           // packed dec weights

    float* z    = (float*)d_out;
    float* xrec = (float*)d_out + (size_t)N * HDIM;

    // 1) pack weights
    k_prep<<<32, 256, 0, stream>>>(W_enc, wpe, W_dec, wpd);

    // 2) fused: GEMM1 || P1a bucket histograms (no global atomics anywhere)
    k_fused<<<G1 + 256, 256, 0, stream>>>(x, wpe, hb, N, col, bcnt, E, NBKT, EPB, G1);

    // 3) hierarchical exclusive scan of (bin,blk) counts
    k_scanB1<<<SB, 256, 0, stream>>>(bcnt, bsum, M);
    k_scanB2<<<1, 128, 0, stream>>>(bsum, bofs, bbase, SB, M);
    k_scanB3<<<SB, 256, 0, stream>>>(bcnt, bofs, bbase, M);

    // 4) partition edges into buckets (packed entries)
    k_p1b<<<256, 256, 0, stream>>>(row, col, bbase, pbuf, E, NBKT, EPB);

    // 5) per-bucket CSR build + dinv + hb pre-scale (LDS atomics only)
    k_p2<<<NBKT, 256, 0, stream>>>(pbuf, bbase, ebuf, goff, gcnt, dinv, (unsigned*)hb, N, E);

    // 6) z = relu(dc * sum(hb') + b_enc)  (+ bf16 copy zb; pbuf dead now)
    k_agg<<<(N + 3) / 4, 256, 0, stream>>>(ebuf, goff, gcnt, dinv, (const unsigned*)hb, b_enc, z, zb, N);

    // 7) x_recon = zb @ W_dec^T + b_dec
    k_gemm2<<<G1, 256, 0, stream>>>(zb, wpd, b_dec, xrec, N);
}